// Round 3
// baseline (458.043 us; speedup 1.0000x reference)
//
#include <hip/hip_runtime.h>

// Problem: N=65536 rows, C=100 classes, 6 matrices (outputs1..5, mimic).
// out[0]            = max over ALL elements of outputs1..5
// out[1 + row*6 + j]= softmax_j(margins(row)/TEMP), TEMP=2
// margin(x,t) = (x[t] == max(x)) ? max(x) - second_max(x) : 0
//
// R10: R8 (coalesced LDS, 77us) and R9 (wave-coop 24-lines/instr, 74us) both
// LOST to the max-scatter R0 (61.6us) -> line-request count is NOT the
// bottleneck; the ~61us load wall is latency/miss-service bound and layout-
// invariant. This round keeps R0's margin structure EXACTLY and instead
// eliminates the second dispatch: softmax is fused via a last-arriving-block
// scheme (agent-scope acq_rel counters per row-tile), and out[0] decode via a
// global completion counter. Removes softmax kernel + inter-kernel gap.

constexpr int C = 100;
constexpr float INV_TEMP = 0.5f;   // 1/TEMP

// Order-preserving float -> unsigned encoding for atomicMax.
// enc(f) >= enc(-inf) = 0x007FFFFF > 0, so memset-0 is a valid identity.
__device__ __forceinline__ unsigned enc_f(float f) {
    unsigned u = __float_as_uint(f);
    return (u & 0x80000000u) ? ~u : (u | 0x80000000u);
}

// Grid: (nblk, 6), block 256. Thread = (row, half, matrix); 128 rows/block.
// ws[0] = enc running max, ws[1] = global block counter,
// ws[2+x] = per-tile counter (only when fuse=1).
__global__ __launch_bounds__(256, 8) void margin_kernel(
    const float* __restrict__ o1, const float* __restrict__ o2,
    const float* __restrict__ o3, const float* __restrict__ o4,
    const float* __restrict__ o5, const float* __restrict__ mimic,
    const int* __restrict__ tgt, float* __restrict__ out,
    unsigned* __restrict__ ws, int n, int nblk, int fuse)
{
    __shared__ unsigned wmax[4];
    __shared__ unsigned sflag;

    const int m    = blockIdx.y;                       // 0..5 (uniform)
    const int tid  = threadIdx.x;
    const int tid2 = blockIdx.x * 256 + tid;
    const int row  = tid2 >> 1;                        // partner pair = lanes 2k,2k+1
    const int half = tid2 & 1;                         // 0: f4[0,13), 1: f4[13,25)
    const int lane = tid & 63;

    const float* __restrict__ mat =
        (m == 0) ? o1 : (m == 1) ? o2 : (m == 2) ? o3 :
        (m == 3) ? o4 : (m == 4) ? o5 : mimic;

    // int32-vs-int64 target layout detection (wave-uniform).
    // int64 little-endian nonneg => odd 32-bit words all zero.
    const int pidx  = 2 * lane + 1;
    const int probe = (pidx < n) ? tgt[pidx] : 0;
    const unsigned long long nz = __ballot(probe != 0);
    const int tstride = (nz == 0ull) ? 2 : 1;

    float rowM1 = -INFINITY;   // post-merge row max (for global max reduce)

    if (row < n) {             // partner lanes agree on this predicate
        const size_t rowoff = (size_t)row * C;
        const float4* __restrict__ p4 =
            (const float4*)(mat + rowoff) + (half ? 13 : 0);

        // 4 independent top-2 trackers (ILP on the fmax chains)
        float m1x = -INFINITY, m2x = -INFINITY;
        float m1y = -INFINITY, m2y = -INFINITY;
        float m1z = -INFINITY, m2z = -INFINITY;
        float m1w = -INFINITY, m2w = -INFINITY;
        #pragma unroll
        for (int i = 0; i < 12; ++i) {   // both halves: 12 f4s
            const float4 v = p4[i];
            m2x = fmaxf(m2x, fminf(m1x, v.x)); m1x = fmaxf(m1x, v.x);
            m2y = fmaxf(m2y, fminf(m1y, v.y)); m1y = fmaxf(m1y, v.y);
            m2z = fmaxf(m2z, fminf(m1z, v.z)); m1z = fmaxf(m1z, v.z);
            m2w = fmaxf(m2w, fminf(m1w, v.w)); m1w = fmaxf(m1w, v.w);
        }
        if (!half) {                     // half 0 owns the 13th f4 (index 12)
            const float4 v = p4[12];
            m2x = fmaxf(m2x, fminf(m1x, v.x)); m1x = fmaxf(m1x, v.x);
            m2y = fmaxf(m2y, fminf(m1y, v.y)); m1y = fmaxf(m1y, v.y);
            m2z = fmaxf(m2z, fminf(m1z, v.z)); m1z = fmaxf(m1z, v.z);
            m2w = fmaxf(m2w, fminf(m1w, v.w)); m1w = fmaxf(m1w, v.w);
        }
        // merge 4 trackers -> this thread's (tm1, tm2)
        const float m1xy = fmaxf(m1x, m1y);
        const float m2xy = fmaxf(fminf(m1x, m1y), fmaxf(m2x, m2y));
        const float m1zw = fmaxf(m1z, m1w);
        const float m2zw = fmaxf(fminf(m1z, m1w), fmaxf(m2z, m2w));
        const float tm1  = fmaxf(m1xy, m1zw);
        const float tm2  = fmaxf(fminf(m1xy, m1zw), fmaxf(m2xy, m2zw));

        // merge with partner (lane^1; halves are disjoint -> exact)
        const float p1 = __shfl_xor(tm1, 1);
        const float p2 = __shfl_xor(tm2, 1);
        const float M1 = fmaxf(tm1, p1);
        const float M2 = fmaxf(fminf(tm1, p1), fmaxf(tm2, p2));

        const int   t  = tgt[(size_t)row * tstride];   // 0..99 (both partners)
        const float tv = mat[rowoff + t];              // L1-hit, same value both
        if (!half)
            out[1 + (size_t)row * 6 + m] = (tv == M1) ? (M1 - M2) * INV_TEMP : 0.0f;
        rowM1 = M1;
    }

    // global max over matrices 0..4: wave reduce, 4-slot LDS, 1 atomic/block
    #pragma unroll
    for (int s = 1; s < 64; s <<= 1) rowM1 = fmaxf(rowM1, __shfl_xor(rowM1, s));
    if (lane == 0) wmax[tid >> 6] = enc_f(rowM1);
    if (tid == 0) sflag = 0;
    __syncthreads();   // also drains vmcnt: all margin stores are in L2 now

    if (tid == 0) {
        if (m < 5)
            atomicMax(ws, max(max(wmax[0], wmax[1]), max(wmax[2], wmax[3])));
        if (fuse) {
            // publish this block's margins / acquire the other 5 blocks'
            const unsigned done = __hip_atomic_fetch_add(
                &ws[2 + blockIdx.x], 1u,
                __ATOMIC_ACQ_REL, __HIP_MEMORY_SCOPE_AGENT);
            sflag = done;                 // 5 => we finish this tile
            // global completion -> decode out[0]
            const unsigned g = __hip_atomic_fetch_add(
                &ws[1], 1u, __ATOMIC_ACQ_REL, __HIP_MEMORY_SCOPE_AGENT);
            if (g == (unsigned)(6 * nblk - 1)) {
                const unsigned e = __hip_atomic_load(
                    &ws[0], __ATOMIC_RELAXED, __HIP_MEMORY_SCOPE_AGENT);
                const unsigned bits = (e & 0x80000000u) ? (e & 0x7FFFFFFFu) : ~e;
                out[0] = __uint_as_float(bits);
            }
        }
    }
    __syncthreads();

    if (sflag == 5u) {
        // last block of this row-tile: in-place 6-wide softmax for 128 rows
        const int r0 = blockIdx.x * 128;
        if (tid < 128) {
            const int rr = r0 + tid;
            if (rr < n) {
                float* p = out + 1 + (size_t)rr * 6;
                float v[6];
                #pragma unroll
                for (int j = 0; j < 6; ++j) v[j] = p[j];
                float mx = v[0];
                #pragma unroll
                for (int j = 1; j < 6; ++j) mx = fmaxf(mx, v[j]);
                float e6[6], s = 0.0f;
                #pragma unroll
                for (int j = 0; j < 6; ++j) { e6[j] = __expf(v[j] - mx); s += e6[j]; }
                const float inv = 1.0f / s;
                #pragma unroll
                for (int j = 0; j < 6; ++j) p[j] = e6[j] * inv;
            }
        }
    }
}

// Fallback path only (ws too small to hold tile counters):
// in-place 6-wide softmax over out[1+row*6 .. +5]; thread 0 decodes out[0].
__global__ __launch_bounds__(256) void softmax_kernel(
    float* __restrict__ out, const unsigned* __restrict__ ws, int n)
{
    const int row = blockIdx.x * blockDim.x + threadIdx.x;
    if (row < n) {
        float* p = out + 1 + (size_t)row * 6;
        float mrg[6];
        #pragma unroll
        for (int j = 0; j < 6; ++j) mrg[j] = p[j];
        float mx = mrg[0];
        #pragma unroll
        for (int j = 1; j < 6; ++j) mx = fmaxf(mx, mrg[j]);
        float e[6], s = 0.0f;
        #pragma unroll
        for (int j = 0; j < 6; ++j) { e[j] = __expf(mrg[j] - mx); s += e[j]; }
        const float inv = 1.0f / s;
        #pragma unroll
        for (int j = 0; j < 6; ++j) p[j] = e[j] * inv;
    }
    if (row == 0) {
        const unsigned e = ws[0];
        const unsigned bits = (e & 0x80000000u) ? (e & 0x7FFFFFFFu) : ~e;
        out[0] = __uint_as_float(bits);
    }
}

extern "C" void kernel_launch(void* const* d_in, const int* in_sizes, int n_in,
                              void* d_out, int out_size, void* d_ws, size_t ws_size,
                              hipStream_t stream) {
    const float* o1    = (const float*)d_in[0];
    const float* o2    = (const float*)d_in[1];
    const float* o3    = (const float*)d_in[2];
    const float* o4    = (const float*)d_in[3];
    const float* o5    = (const float*)d_in[4];
    const float* mimic = (const float*)d_in[5];
    const int*   tgt   = (const int*)d_in[6];
    float*       out   = (float*)d_out;
    unsigned*    ws    = (unsigned*)d_ws;

    const int n    = in_sizes[6];            // N = 65536
    const int nblk = (2 * n + 255) / 256;    // 512 row-tiles of 128 rows

    const size_t need = (size_t)(2 + nblk) * sizeof(unsigned);
    const int fuse = (ws_size >= need) ? 1 : 0;

    // counters + encoded max; 0 is the identity for both.
    hipMemsetAsync(ws, 0, fuse ? need : sizeof(unsigned), stream);

    dim3 grid(nblk, 6);   // 512 x 6 = 3072 blocks, 12288 waves
    margin_kernel<<<grid, 256, 0, stream>>>(o1, o2, o3, o4, o5, mimic,
                                            tgt, out, ws, n, nblk, fuse);
    if (!fuse)
        softmax_kernel<<<(n + 255) / 256, 256, 0, stream>>>(out, ws, n);
}

// Round 4
// 183.546 us; speedup vs baseline: 2.4955x; 2.4955x over previous
//
#include <hip/hip_runtime.h>

// Problem: N=65536 rows, C=100 classes, 6 matrices (outputs1..5, mimic).
// out[0]            = max over ALL elements of outputs1..5
// out[1 + row*6 + j]= softmax_j(margins(row)/TEMP), TEMP=2
// margin(x,t) = (x[t] == max(x)) ? max(x) - second_max(x) : 0
//
// R11: R10's fused acq_rel-atomic scheme was catastrophic (337us margin:
// agent-scope ACQ_REL fetch_add per block => L2 writeback/inv serialization).
// REVERTED to R0's two-kernel scatter structure (61.6us margin, best known).
// R10 also proved total-minus-margin ~= 120us is fixed harness overhead
// (identical with and without the softmax kernel), so margin is the only lever.
// Single change vs R0: load ALL 13 float4s into named regs BEFORE reducing.
// R0's VGPR_Count=32 allocation kept only ~3-4 loads in flight (compiler
// chose occupancy over MLP); Little's law at ~500cy L2/L3 service = ~32
// outstanding lines/CU = the observed 2.5 TB/s wall. launch_bounds(256,6)
// lifts the reg cap to ~84 (52 data regs fit); 3-4x per-wave MLP at
// unchanged wave count. Pure A/B on load scheduling.

constexpr int C = 100;
constexpr float INV_TEMP = 0.5f;   // 1/TEMP

// Order-preserving float -> unsigned encoding for atomicMax.
// enc(f) >= enc(-inf) = 0x007FFFFF > 0, so memset-0 is a valid identity.
__device__ __forceinline__ unsigned enc_f(float f) {
    unsigned u = __float_as_uint(f);
    return (u & 0x80000000u) ? ~u : (u | 0x80000000u);
}

__device__ __forceinline__ void t2(float& m1, float& m2, float v) {
    m2 = fmaxf(m2, fminf(m1, v));
    m1 = fmaxf(m1, v);
}

// Grid: (ceil(2n/256), 6). Block: 256 threads. Thread = (row, half, matrix).
__global__ __launch_bounds__(256, 6) void margin_kernel(
    const float* __restrict__ o1, const float* __restrict__ o2,
    const float* __restrict__ o3, const float* __restrict__ o4,
    const float* __restrict__ o5, const float* __restrict__ mimic,
    const int* __restrict__ tgt, float* __restrict__ out,
    unsigned* __restrict__ ws, int n)
{
    __shared__ unsigned wmax[4];

    const int m    = blockIdx.y;                       // 0..5 (uniform)
    const int tid2 = blockIdx.x * 256 + threadIdx.x;
    const int row  = tid2 >> 1;                        // partner pair = lanes 2k,2k+1
    const int half = tid2 & 1;                         // 0: f4[0,13), 1: f4[13,25)
    const int lane = threadIdx.x & 63;

    const float* __restrict__ mat =
        (m == 0) ? o1 : (m == 1) ? o2 : (m == 2) ? o3 :
        (m == 3) ? o4 : (m == 4) ? o5 : mimic;

    // int32-vs-int64 target layout detection (wave-uniform).
    // int64 little-endian nonneg => odd 32-bit words all zero.
    const int pidx  = 2 * lane + 1;
    const int probe = (pidx < n) ? tgt[pidx] : 0;
    const unsigned long long nz = __ballot(probe != 0);
    const int tstride = (nz == 0ull) ? 2 : 1;

    float rowM1 = -INFINITY;   // post-merge row max (for global max reduce)

    if (row < n) {             // partner lanes agree on this predicate
        const size_t rowoff = (size_t)row * C;
        const float4* __restrict__ p4 =
            (const float4*)(mat + rowoff) + (half ? 13 : 0);

        // ---- issue ALL loads first: 13 named float4s, one deep vmcnt queue ----
        const float4 v0  = p4[0];
        const float4 v1  = p4[1];
        const float4 v2  = p4[2];
        const float4 v3  = p4[3];
        const float4 v4  = p4[4];
        const float4 v5  = p4[5];
        const float4 v6  = p4[6];
        const float4 v7  = p4[7];
        const float4 v8  = p4[8];
        const float4 v9  = p4[9];
        const float4 v10 = p4[10];
        const float4 v11 = p4[11];
        float4 v12 = make_float4(-INFINITY, -INFINITY, -INFINITY, -INFINITY);
        if (!half) v12 = p4[12];   // half 0 owns the 13th f4 (exec-masked load)

        // ---- 4 independent top-2 trackers (ILP on the fmax chains) ----
        float m1x = -INFINITY, m2x = -INFINITY;
        float m1y = -INFINITY, m2y = -INFINITY;
        float m1z = -INFINITY, m2z = -INFINITY;
        float m1w = -INFINITY, m2w = -INFINITY;
        t2(m1x,m2x,v0.x);  t2(m1y,m2y,v0.y);  t2(m1z,m2z,v0.z);  t2(m1w,m2w,v0.w);
        t2(m1x,m2x,v1.x);  t2(m1y,m2y,v1.y);  t2(m1z,m2z,v1.z);  t2(m1w,m2w,v1.w);
        t2(m1x,m2x,v2.x);  t2(m1y,m2y,v2.y);  t2(m1z,m2z,v2.z);  t2(m1w,m2w,v2.w);
        t2(m1x,m2x,v3.x);  t2(m1y,m2y,v3.y);  t2(m1z,m2z,v3.z);  t2(m1w,m2w,v3.w);
        t2(m1x,m2x,v4.x);  t2(m1y,m2y,v4.y);  t2(m1z,m2z,v4.z);  t2(m1w,m2w,v4.w);
        t2(m1x,m2x,v5.x);  t2(m1y,m2y,v5.y);  t2(m1z,m2z,v5.z);  t2(m1w,m2w,v5.w);
        t2(m1x,m2x,v6.x);  t2(m1y,m2y,v6.y);  t2(m1z,m2z,v6.z);  t2(m1w,m2w,v6.w);
        t2(m1x,m2x,v7.x);  t2(m1y,m2y,v7.y);  t2(m1z,m2z,v7.z);  t2(m1w,m2w,v7.w);
        t2(m1x,m2x,v8.x);  t2(m1y,m2y,v8.y);  t2(m1z,m2z,v8.z);  t2(m1w,m2w,v8.w);
        t2(m1x,m2x,v9.x);  t2(m1y,m2y,v9.y);  t2(m1z,m2z,v9.z);  t2(m1w,m2w,v9.w);
        t2(m1x,m2x,v10.x); t2(m1y,m2y,v10.y); t2(m1z,m2z,v10.z); t2(m1w,m2w,v10.w);
        t2(m1x,m2x,v11.x); t2(m1y,m2y,v11.y); t2(m1z,m2z,v11.z); t2(m1w,m2w,v11.w);
        t2(m1x,m2x,v12.x); t2(m1y,m2y,v12.y); t2(m1z,m2z,v12.z); t2(m1w,m2w,v12.w);

        // merge 4 trackers -> this thread's (tm1, tm2)
        const float m1xy = fmaxf(m1x, m1y);
        const float m2xy = fmaxf(fminf(m1x, m1y), fmaxf(m2x, m2y));
        const float m1zw = fmaxf(m1z, m1w);
        const float m2zw = fmaxf(fminf(m1z, m1w), fmaxf(m2z, m2w));
        const float tm1  = fmaxf(m1xy, m1zw);
        const float tm2  = fmaxf(fminf(m1xy, m1zw), fmaxf(m2xy, m2zw));

        // merge with partner (lane^1; halves are disjoint -> exact)
        const float p1 = __shfl_xor(tm1, 1);
        const float p2 = __shfl_xor(tm2, 1);
        const float M1 = fmaxf(tm1, p1);
        const float M2 = fmaxf(fminf(tm1, p1), fmaxf(tm2, p2));

        const int   t  = tgt[(size_t)row * tstride];   // 0..99 (both partners)
        const float tv = mat[rowoff + t];              // L1-hit, same value both
        if (!half)
            out[1 + (size_t)row * 6 + m] = (tv == M1) ? (M1 - M2) * INV_TEMP : 0.0f;
        rowM1 = M1;
    }

    // global max over matrices 0..4: wave reduce, 4-slot LDS, 1 atomic/block
    #pragma unroll
    for (int s = 1; s < 64; s <<= 1) rowM1 = fmaxf(rowM1, __shfl_xor(rowM1, s));
    if (m < 5) {                                  // block-uniform branch
        if (lane == 0) wmax[threadIdx.x >> 6] = enc_f(rowM1);
        __syncthreads();
        if (threadIdx.x == 0) {
            const unsigned u = max(max(wmax[0], wmax[1]), max(wmax[2], wmax[3]));
            atomicMax(ws, u);
        }
    }
}

// In-place 6-wide softmax over out[1+row*6 .. +5]; thread 0 decodes out[0].
__global__ __launch_bounds__(256) void softmax_kernel(
    float* __restrict__ out, const unsigned* __restrict__ ws, int n)
{
    const int row = blockIdx.x * blockDim.x + threadIdx.x;
    if (row < n) {
        float* p = out + 1 + (size_t)row * 6;
        float mrg[6];
        #pragma unroll
        for (int j = 0; j < 6; ++j) mrg[j] = p[j];
        float mx = mrg[0];
        #pragma unroll
        for (int j = 1; j < 6; ++j) mx = fmaxf(mx, mrg[j]);
        float e[6], s = 0.0f;
        #pragma unroll
        for (int j = 0; j < 6; ++j) { e[j] = __expf(mrg[j] - mx); s += e[j]; }
        const float inv = 1.0f / s;
        #pragma unroll
        for (int j = 0; j < 6; ++j) p[j] = e[j] * inv;
    }
    if (row == 0) {
        const unsigned e = ws[0];
        const unsigned bits = (e & 0x80000000u) ? (e & 0x7FFFFFFFu) : ~e;
        out[0] = __uint_as_float(bits);
    }
}

extern "C" void kernel_launch(void* const* d_in, const int* in_sizes, int n_in,
                              void* d_out, int out_size, void* d_ws, size_t ws_size,
                              hipStream_t stream) {
    const float* o1    = (const float*)d_in[0];
    const float* o2    = (const float*)d_in[1];
    const float* o3    = (const float*)d_in[2];
    const float* o4    = (const float*)d_in[3];
    const float* o5    = (const float*)d_in[4];
    const float* mimic = (const float*)d_in[5];
    const int*   tgt   = (const int*)d_in[6];
    float*       out   = (float*)d_out;
    unsigned*    ws    = (unsigned*)d_ws;

    const int n = in_sizes[6];   // N = 65536

    // ws[0] = encoded running max; 0 is the identity for the encoding.
    hipMemsetAsync(ws, 0, sizeof(unsigned), stream);

    dim3 grid((2 * n + 255) / 256, 6);   // 512 x 6 = 3072 blocks, 12288 waves
    margin_kernel<<<grid, 256, 0, stream>>>(o1, o2, o3, o4, o5, mimic,
                                            tgt, out, ws, n);
    softmax_kernel<<<(n + 255) / 256, 256, 0, stream>>>(out, ws, n);
}